// Round 5
// baseline (12178.194 us; speedup 1.0000x reference)
//
#include <hip/hip_runtime.h>
#include <hip/hip_bf16.h>
#include <hip/hip_cooperative_groups.h>

namespace cg = cooperative_groups;

typedef __bf16 bf16x8 __attribute__((ext_vector_type(8)));
typedef float f32x4 __attribute__((ext_vector_type(4)));

#define HSZ (1024*512)      // h/c slot elems
#define WSZ (2048*512)      // weight matrix elems

__device__ __forceinline__ float fsig(float x){ return 1.0f/(1.0f+__expf(-x)); }
__device__ __forceinline__ float ftanh(float x){ return 1.0f - 2.0f/(__expf(2.0f*x)+1.0f); }

__device__ __forceinline__ void gload16(const void* g, void* l){
  __builtin_amdgcn_global_load_lds((const __attribute__((address_space(1))) void*)g,
                                   (__attribute__((address_space(3))) void*)l, 16, 0, 0);
}

struct Tid { int w, lane, wm, wn, colL, kgrp, srow, scch; };
__device__ __forceinline__ Tid mkTid(){
  Tid T; T.w = threadIdx.x >> 6; T.lane = threadIdx.x & 63;
  T.wm = T.w >> 1; T.wn = T.w & 1; T.colL = T.lane & 15; T.kgrp = T.lane >> 4;
  T.srow = T.lane >> 3; T.scch = T.lane & 7; return T;
}

struct SegT { const ushort* A; const ushort* W; };
struct CellD { int endit; const float* xs; const float* Ws; int ks;
               const float* bias; float* c; ushort* h; int valid; };

// stage one 64-K tile (A 64x64 + B 128x64 h-major-gate rows) into ring buffer `buf`
__device__ __forceinline__ void stage_buf(const ushort* A, const ushort* W, int k0,
                                          char* ldsb, int buf, int m0, int h0q, const Tid& T){
  ushort* Als = (ushort*)(ldsb + buf*24576);
  ushort* Bls = Als + 4096;
  #pragma unroll
  for (int q = 0; q < 2; ++q){
    const int base = (T.w<<4) + (q<<3);
    const int r = base + T.srow;
    const int sw = (T.scch ^ (r & 7)) << 3;
    gload16(A + (size_t)(m0 + r)*512 + k0 + sw, Als + base*64);
  }
  #pragma unroll
  for (int q = 0; q < 4; ++q){
    const int base = (T.w<<5) + (q<<3);
    const int r = base + T.srow;
    const int g = (r >> 4) & 3, hp = r >> 6, hh = r & 15;
    const int sw = (T.scch ^ (r & 7)) << 3;
    gload16(W + ((size_t)(g<<9) + h0q + (hp<<4) + hh)*512 + k0 + sw, Bls + base*64);
  }
}

__device__ __forceinline__ void mfma_step(char* ldsb, int buf, const Tid& T, f32x4 acc[2][4]){
  const ushort* Als = (const ushort*)(ldsb + buf*24576);
  const ushort* Bls = Als + 4096;
  const int ar0 = (T.wm<<5) + T.colL, ar1 = ar0 + 16;
  __builtin_amdgcn_s_setprio(1);
  #pragma unroll
  for (int kh = 0; kh < 2; ++kh){
    const int cb = (kh<<2) + T.kgrp;
    bf16x8 av0 = *(const bf16x8*)(Als + ar0*64 + ((cb ^ (ar0 & 7)) << 3));
    bf16x8 av1 = *(const bf16x8*)(Als + ar1*64 + ((cb ^ (ar1 & 7)) << 3));
    #pragma unroll
    for (int nf = 0; nf < 4; ++nf){
      const int br = (T.wn<<6) + (nf<<4) + T.colL;
      bf16x8 bv = *(const bf16x8*)(Bls + br*64 + ((cb ^ (br & 7)) << 3));
      acc[0][nf] = __builtin_amdgcn_mfma_f32_16x16x32_bf16(av0, bv, acc[0][nf], 0, 0, 0);
      acc[1][nf] = __builtin_amdgcn_mfma_f32_16x16x32_bf16(av1, bv, acc[1][nf], 0, 0, 0);
    }
  }
  __builtin_amdgcn_s_setprio(0);
}

__device__ __forceinline__ void cell_epi(const CellD& C, f32x4 acc[2][4], int m0, int h0q, const Tid& T){
  const int h = h0q + (T.wn<<4) + T.colL;
  float bia[4], wsv[4][4];
  #pragma unroll
  for (int g = 0; g < 4; ++g) bia[g] = C.bias[(g<<9) + h];
  if (C.ks > 0){
    #pragma unroll
    for (int g = 0; g < 4; ++g)
      #pragma unroll
      for (int k = 0; k < 4; ++k)
        wsv[g][k] = (k < C.ks) ? C.Ws[(size_t)((g<<9) + h)*C.ks + k] : 0.f;
  }
  #pragma unroll
  for (int mf = 0; mf < 2; ++mf){
    const int mB = m0 + (T.wm<<5) + (mf<<4) + (T.kgrp<<2);
    float xv[4][4];
    if (C.ks > 0){
      #pragma unroll
      for (int r = 0; r < 4; ++r)
        #pragma unroll
        for (int k = 0; k < 4; ++k)
          xv[r][k] = (k < C.ks) ? C.xs[(size_t)(mB + r)*C.ks + k] : 0.f;
    }
    #pragma unroll
    for (int r = 0; r < 4; ++r){
      const int m = mB + r;
      float gv[4];
      #pragma unroll
      for (int g = 0; g < 4; ++g){
        float t_ = acc[mf][g][r] + bia[g];
        if (C.ks > 0){
          #pragma unroll
          for (int k = 0; k < 4; ++k) t_ += xv[r][k]*wsv[g][k];
        }
        gv[g] = t_;
      }
      const float iG = fsig(gv[0]);
      const float fG = fsig(gv[1]);
      const float gG = ftanh(gv[2]);
      const float oG = fsig(gv[3]);
      const size_t off = (size_t)m*512 + h;
      const float cn = fG*C.c[off] + iG*gG;
      C.c[off] = cn;
      const float hv = oG*ftanh(cn);
      __hip_bfloat16 hb = __float2bfloat16(hv);
      C.h[off] = *reinterpret_cast<const ushort*>(&hb);
    }
  }
}

// one continuous pipelined stream of NT 64-K steps over <=5 segments / <=3 cells.
// ring-4 buffers, depth-3 prefetch, ONE barrier per K-step, counted vmcnt(12).
__device__ __forceinline__ void run_step(const SegT* seg, const CellD* cell, int ncell, int NT,
                                         char* ldsb, int m0, int h0q, const Tid& T){
  f32x4 acc[2][4];
  #pragma unroll
  for (int a = 0; a < 2; ++a)
    #pragma unroll
    for (int b = 0; b < 4; ++b)
      #pragma unroll
      for (int c = 0; c < 4; ++c) acc[a][b][c] = 0.f;

  auto sel = [&](int sgi, const ushort*& A, const ushort*& W){
    switch (sgi){
      case 0:  A = seg[0].A; W = seg[0].W; break;
      case 1:  A = seg[1].A; W = seg[1].W; break;
      case 2:  A = seg[2].A; W = seg[2].W; break;
      case 3:  A = seg[3].A; W = seg[3].W; break;
      default: A = seg[4].A; W = seg[4].W; break;
    }
  };

  #pragma unroll
  for (int it = 0; it < 3; ++it){
    const ushort *A, *W; sel(it >> 3, A, W);
    stage_buf(A, W, (it & 7) << 6, ldsb, it, m0, h0q, T);
  }
  for (int it = 0; it < NT; ++it){
    if (it < NT-2)       asm volatile("s_waitcnt vmcnt(12)" ::: "memory");
    else if (it == NT-2) asm volatile("s_waitcnt vmcnt(6)"  ::: "memory");
    else                 asm volatile("s_waitcnt vmcnt(0)"  ::: "memory");
    __builtin_amdgcn_s_barrier();
    __builtin_amdgcn_sched_barrier(0);
    if (it + 3 < NT){
      const int jt = it + 3;
      const ushort *A, *W; sel(jt >> 3, A, W);
      stage_buf(A, W, (jt & 7) << 6, ldsb, jt & 3, m0, h0q, T);
    }
    mfma_step(ldsb, it & 3, T, acc);
    __builtin_amdgcn_sched_barrier(0);
    bool bnd = false;
    if (it == cell[0].endit){ if (cell[0].valid) cell_epi(cell[0], acc, m0, h0q, T); bnd = true; }
    if (ncell > 1 && it == cell[1].endit){ if (cell[1].valid) cell_epi(cell[1], acc, m0, h0q, T); bnd = true; }
    if (ncell > 2 && it == cell[2].endit){ if (cell[2].valid) cell_epi(cell[2], acc, m0, h0q, T); bnd = true; }
    if (bnd){
      #pragma unroll
      for (int a = 0; a < 2; ++a)
        #pragma unroll
        for (int b = 0; b < 4; ++b)
          #pragma unroll
          for (int c = 0; c < 4; ++c) acc[a][b][c] = 0.f;
    }
  }
}

// ---------------- encoder ----------------
struct EncP { const float* x; const float* Wih0f;
  const ushort *Whh0, *Wih1, *Whh1, *Wih2, *Whh2;
  const float* biases; ushort *h0, *h1, *h2; float *c0, *c1, *c2; };

// wavefront step s: l0 t=s (K=512), l1 t=s-1 (K=1024), l2 t=s-2 (K=1024); h slots indexed by t&1
__device__ __forceinline__ void enc_build_run(const EncP& E, int s, char* lds, int m0, int h0q, const Tid& T){
  const int p = s & 1;
  SegT seg[5] = {
    { E.h0 + (size_t)(p^1)*HSZ, E.Whh0 },
    { E.h0 + (size_t)(p^1)*HSZ, E.Wih1 },
    { E.h1 + (size_t)p*HSZ,     E.Whh1 },
    { E.h1 + (size_t)p*HSZ,     E.Wih2 },
    { E.h2 + (size_t)(p^1)*HSZ, E.Whh2 },
  };
  CellD cell[3] = {
    { 7,  E.x + (size_t)(s <= 63 ? s : 63)*4096, E.Wih0f, 4, E.biases,      E.c0, E.h0 + (size_t)p*HSZ,     (int)(s <= 63) },
    { 23, nullptr, nullptr, 0,                   E.biases + 2048, E.c1, E.h1 + (size_t)(p^1)*HSZ, (int)(s >= 1 && s <= 64) },
    { 39, nullptr, nullptr, 0,                   E.biases + 4096, E.c2, E.h2 + (size_t)p*HSZ,     (int)(s >= 2) },
  };
  run_step(seg, cell, 3, 40, lds, m0, h0q, T);
}

__device__ __forceinline__ void wgmap(int f, int& m0, int& h0q){
  const int xcd = f & 7, j = f >> 3;
  m0  = (j & 15) << 6;
  h0q = (((j >> 4) << 3) + xcd) << 5;
}

__global__ __launch_bounds__(256) void enc_persist(EncP E){
  __shared__ char lds[98304];
  const Tid T = mkTid();
  int m0, h0q; wgmap(blockIdx.x, m0, h0q);
  cg::grid_group g = cg::this_grid();
  for (int s = 0; s < 66; ++s){
    enc_build_run(E, s, lds, m0, h0q, T);
    if (s != 65){ __threadfence(); g.sync(); }
  }
}

__global__ __launch_bounds__(256) void enc_step_k(EncP E, int s){
  __shared__ char lds[98304];
  const Tid T = mkTid();
  int m0, h0q; wgmap(blockIdx.x, m0, h0q);
  enc_build_run(E, s, lds, m0, h0q, T);
}

// ---------------- decoder ----------------
struct PhaseP { const ushort *A0, *W0, *A1, *W1; int nseg;
  const float *xs, *Ws; int ks; const float* bias; float* c; ushort* h; };

__device__ __forceinline__ void phase_run(const PhaseP& P, char* lds, int m0, int h0q, const Tid& T){
  SegT seg[5];
  seg[0] = { P.A0, P.W0 };
  seg[1] = (P.nseg > 1) ? SegT{ P.A1, P.W1 } : seg[0];
  seg[2] = seg[1]; seg[3] = seg[1]; seg[4] = seg[1];
  const int NT = P.nseg * 8;
  CellD cell[3];
  cell[0] = { NT - 1, P.xs, P.Ws, P.ks, P.bias, P.c, P.h, 1 };
  cell[1] = cell[0]; cell[1].endit = -1; cell[1].valid = 0;
  cell[2] = cell[1];
  run_step(seg, cell, 1, NT, lds, m0, h0q, T);
}

struct DecP { const float* dec_in; const float* Wih0f;
  const ushort *wcomb, *Whh0, *Wih1, *Whh1, *Wih2, *Whh2;
  const float* biases; ushort *h0, *h1, *h2enc, *h2hist; float *c0, *c1, *c2; };

__global__ __launch_bounds__(256) void dec_persist(DecP D){
  __shared__ char lds[98304];
  const Tid T = mkTid();
  int m0, h0q; wgmap(blockIdx.x, m0, h0q);
  cg::grid_group g = cg::this_grid();
  int cur0 = 1, cur1 = 1;
  for (int t = 0; t < 32; ++t){
    PhaseP P0;
    if (t == 0) P0 = { D.h0 + (size_t)cur0*HSZ, D.Whh0, nullptr, nullptr, 1,
                       D.dec_in, D.Wih0f, 2, D.biases + 3*2048, D.c0, D.h0 + (size_t)(cur0^1)*HSZ };
    else        P0 = { D.h2hist + (size_t)(t-1)*HSZ, D.wcomb, D.h0 + (size_t)cur0*HSZ, D.Whh0, 2,
                       nullptr, nullptr, 0, D.biases + 4*2048, D.c0, D.h0 + (size_t)(cur0^1)*HSZ };
    phase_run(P0, lds, m0, h0q, T); cur0 ^= 1;
    __threadfence(); g.sync();
    PhaseP P1 = { D.h0 + (size_t)cur0*HSZ, D.Wih1, D.h1 + (size_t)cur1*HSZ, D.Whh1, 2,
                  nullptr, nullptr, 0, D.biases + 5*2048, D.c1, D.h1 + (size_t)(cur1^1)*HSZ };
    phase_run(P1, lds, m0, h0q, T); cur1 ^= 1;
    __threadfence(); g.sync();
    const ushort* h2p = (t == 0) ? (D.h2enc + (size_t)HSZ) : (D.h2hist + (size_t)(t-1)*HSZ);
    PhaseP P2 = { D.h1 + (size_t)cur1*HSZ, D.Wih2, h2p, D.Whh2, 2,
                  nullptr, nullptr, 0, D.biases + 6*2048, D.c2, D.h2hist + (size_t)t*HSZ };
    phase_run(P2, lds, m0, h0q, T);
    if (t != 31){ __threadfence(); g.sync(); }
  }
}

__global__ __launch_bounds__(256) void phase_k(PhaseP P){
  __shared__ char lds[98304];
  const Tid T = mkTid();
  int m0, h0q; wgmap(blockIdx.x, m0, h0q);
  phase_run(P, lds, m0, h0q, T);
}

// ---------------- small utility kernels ----------------
__global__ void f2b4(const float4* __restrict__ src, ushort4* __restrict__ dst, int n4){
  int i = blockIdx.x*blockDim.x + threadIdx.x;
  if (i < n4){
    float4 v = src[i];
    __hip_bfloat16 a=__float2bfloat16(v.x), b=__float2bfloat16(v.y), c=__float2bfloat16(v.z), d=__float2bfloat16(v.w);
    ushort4 r;
    r.x = *reinterpret_cast<ushort*>(&a);
    r.y = *reinterpret_cast<ushort*>(&b);
    r.z = *reinterpret_cast<ushort*>(&c);
    r.w = *reinterpret_cast<ushort*>(&d);
    dst[i] = r;
  }
}

__global__ void init_decin(const float* __restrict__ x, float* __restrict__ di){
  int i = blockIdx.x*blockDim.x + threadIdx.x;
  if (i < 2048){ int m = i >> 1, j = i & 1; di[i] = x[(size_t)63*4096 + m*4 + j]; }
}

__global__ void make_wcomb(const float* __restrict__ dWih0, const float* __restrict__ linW,
                           ushort* __restrict__ wc){
  int i = blockIdx.x*blockDim.x + threadIdx.x;
  if (i < 2048*512){
    int n = i >> 9, k = i & 511;
    float v = dWih0[n*2]*linW[k] + dWih0[n*2+1]*linW[512+k];
    __hip_bfloat16 b = __float2bfloat16(v);
    wc[i] = *reinterpret_cast<ushort*>(&b);
  }
}

__global__ void prep_bias(const float* ebih0, const float* ebhh0,
                          const float* ebih, const float* ebhh,
                          const float* dbih0, const float* dbhh0,
                          const float* dbih, const float* dbhh,
                          const float* dWih0, const float* linb, float* bout){
  int n = blockIdx.x*blockDim.x + threadIdx.x;
  if (n >= 2048) return;
  bout[n]        = ebih0[n] + ebhh0[n];
  bout[2048+n]   = ebih[n] + ebhh[n];
  bout[2*2048+n] = ebih[2048+n] + ebhh[2048+n];
  float d0 = dbih0[n] + dbhh0[n];
  bout[3*2048+n] = d0;
  bout[4*2048+n] = d0 + dWih0[n*2]*linb[0] + dWih0[n*2+1]*linb[1];
  bout[5*2048+n] = dbih[n] + dbhh[n];
  bout[6*2048+n] = dbih[2048+n] + dbhh[2048+n];
}

__global__ __launch_bounds__(256) void out_linear(const ushort* __restrict__ h2,
    const float* __restrict__ linW, const float* __restrict__ linb, float* __restrict__ outp){
  int tid = threadIdx.x, w = tid >> 6, lane = tid & 63;
  int rbase = blockIdx.x*32 + w*8;
  for (int r = 0; r < 8; ++r){
    int m = rbase + r;
    float p0 = 0.f, p1 = 0.f;
    #pragma unroll
    for (int kk = 0; kk < 8; ++kk){
      int k = lane + kk*64;
      float hv = __uint_as_float(((unsigned)h2[(size_t)m*512 + k]) << 16);
      p0 += hv * linW[k];
      p1 += hv * linW[512 + k];
    }
    #pragma unroll
    for (int off = 32; off > 0; off >>= 1){
      p0 += __shfl_down(p0, off);
      p1 += __shfl_down(p1, off);
    }
    if (lane == 0){
      outp[(size_t)m*2]   = p0 + linb[0];
      outp[(size_t)m*2+1] = p1 + linb[1];
    }
  }
}

__global__ __launch_bounds__(256) void dec_linear(const ushort* __restrict__ h2,
    const float* __restrict__ linW, const float* __restrict__ linb,
    float* __restrict__ outp, float* __restrict__ di){
  int tid = threadIdx.x, w = tid >> 6, lane = tid & 63;
  int mbase = blockIdx.x*32 + w*8;
  for (int r = 0; r < 8; ++r){
    int m = mbase + r;
    float p0 = 0.f, p1 = 0.f;
    #pragma unroll
    for (int kk = 0; kk < 8; ++kk){
      int k = lane + kk*64;
      float hv = __uint_as_float(((unsigned)h2[(size_t)m*512 + k]) << 16);
      p0 += hv * linW[k];
      p1 += hv * linW[512 + k];
    }
    #pragma unroll
    for (int off = 32; off > 0; off >>= 1){
      p0 += __shfl_down(p0, off);
      p1 += __shfl_down(p1, off);
    }
    if (lane == 0){
      float o0 = p0 + linb[0], o1 = p1 + linb[1];
      outp[m*2]   = o0; outp[m*2+1] = o1;
      di[m*2]     = o0; di[m*2+1]   = o1;
    }
  }
}

extern "C" void kernel_launch(void* const* d_in, const int* in_sizes, int n_in,
                              void* d_out, int out_size, void* d_ws, size_t ws_size,
                              hipStream_t stream)
{
  const float* x        = (const float*)d_in[0];
  const float* enc_Wih0 = (const float*)d_in[1];
  const float* enc_Whh0 = (const float*)d_in[2];
  const float* enc_bih0 = (const float*)d_in[3];
  const float* enc_bhh0 = (const float*)d_in[4];
  const float* enc_Wih  = (const float*)d_in[5];
  const float* enc_Whh  = (const float*)d_in[6];
  const float* enc_bih  = (const float*)d_in[7];
  const float* enc_bhh  = (const float*)d_in[8];
  const float* dec_Wih0 = (const float*)d_in[9];
  const float* dec_Whh0 = (const float*)d_in[10];
  const float* dec_bih0 = (const float*)d_in[11];
  const float* dec_bhh0 = (const float*)d_in[12];
  const float* dec_Wih  = (const float*)d_in[13];
  const float* dec_Whh  = (const float*)d_in[14];
  const float* dec_bih  = (const float*)d_in[15];
  const float* dec_bhh  = (const float*)d_in[16];
  const float* lin_W    = (const float*)d_in[17];
  const float* lin_b    = (const float*)d_in[18];

  const bool big = ws_size >= 69271552ull;

  ushort* wb     = (ushort*)d_ws;
  ushort* eWhh0b = wb;
  ushort* eWihb  = wb + (size_t)WSZ;
  ushort* eWhhb  = wb + 3*(size_t)WSZ;
  ushort* dWhh0b = wb + 5*(size_t)WSZ;
  ushort* dWihb  = wb + 6*(size_t)WSZ;
  ushort* dWhhb  = wb + 8*(size_t)WSZ;
  ushort* wcombb = wb + 10*(size_t)WSZ;                   // big only
  ushort* hbuf   = wb + (big ? 11 : 10)*(size_t)WSZ;      // 6 HSZ (3 layers x 2 slots)
  ushort* h2hist = hbuf + 6*(size_t)HSZ;                  // big: 32 HSZ
  float*  cbuf   = (float*)(h2hist + (big ? 32*(size_t)HSZ : 0));
  float*  dec_in = cbuf + 3*(size_t)HSZ;
  float*  biases = dec_in + 2048;

  ushort* h0 = hbuf;
  ushort* h1 = hbuf + 2*(size_t)HSZ;
  ushort* h2 = hbuf + 4*(size_t)HSZ;
  float *c0 = cbuf, *c1 = cbuf + (size_t)HSZ, *c2 = cbuf + 2*(size_t)HSZ;

  hipMemsetAsync(hbuf, 0, 6*(size_t)HSZ*2, stream);
  hipMemsetAsync(cbuf, 0, 3*(size_t)HSZ*4, stream);

  const int thr = 256;
  {
    struct { const float* s; ushort* d; size_t n; } cv[6] = {
      {enc_Whh0, eWhh0b, WSZ}, {enc_Wih, eWihb, 2*(size_t)WSZ}, {enc_Whh, eWhhb, 2*(size_t)WSZ},
      {dec_Whh0, dWhh0b, WSZ}, {dec_Wih, dWihb, 2*(size_t)WSZ}, {dec_Whh, dWhhb, 2*(size_t)WSZ},
    };
    for (int i = 0; i < 6; ++i){
      int n4 = (int)(cv[i].n/4);
      f2b4<<<(n4+thr-1)/thr, thr, 0, stream>>>((const float4*)cv[i].s, (ushort4*)cv[i].d, n4);
    }
  }
  if (big) make_wcomb<<<4096, thr, 0, stream>>>(dec_Wih0, lin_W, wcombb);
  prep_bias<<<8, thr, 0, stream>>>(enc_bih0, enc_bhh0, enc_bih, enc_bhh,
                                   dec_bih0, dec_bhh0, dec_bih, dec_bhh,
                                   dec_Wih0, lin_b, biases);
  init_decin<<<8, thr, 0, stream>>>(x, dec_in);

  EncP EP = { x, enc_Wih0, eWhh0b, eWihb, eWhhb, eWihb + (size_t)WSZ, eWhhb + (size_t)WSZ,
              biases, h0, h1, h2, c0, c1, c2 };

  // ---- encoder ----
  bool encCoop = false;
  if (big){
    void* ea[] = { (void*)&EP };
    hipError_t e = hipLaunchCooperativeKernel((void*)enc_persist, dim3(256), dim3(256), ea, 0, stream);
    encCoop = (e == hipSuccess);
  }
  if (!encCoop){
    for (int s = 0; s < 66; ++s)
      enc_step_k<<<256, thr, 0, stream>>>(EP, s);
  }

  // encoder-final h slots (t=63 -> slot 1 for all layers)
  const int curF = 1;

  // ---- decoder ----
  if (big){
    DecP DP = { dec_in, dec_Wih0, wcombb, dWhh0b, dWihb, dWhhb,
                dWihb + (size_t)WSZ, dWhhb + (size_t)WSZ,
                biases, h0, h1, h2, h2hist, c0, c1, c2 };
    void* da[] = { (void*)&DP };
    hipError_t e = hipLaunchCooperativeKernel((void*)dec_persist, dim3(256), dim3(256), da, 0, stream);
    if (e != hipSuccess){
      int cur0 = curF, cur1 = curF;
      for (int t = 0; t < 32; ++t){
        PhaseP P0;
        if (t == 0) P0 = { h0 + (size_t)cur0*HSZ, dWhh0b, nullptr, nullptr, 1,
                           dec_in, dec_Wih0, 2, biases + 3*2048, c0, h0 + (size_t)(cur0^1)*HSZ };
        else        P0 = { h2hist + (size_t)(t-1)*HSZ, wcombb, h0 + (size_t)cur0*HSZ, dWhh0b, 2,
                           nullptr, nullptr, 0, biases + 4*2048, c0, h0 + (size_t)(cur0^1)*HSZ };
        phase_k<<<256, thr, 0, stream>>>(P0); cur0 ^= 1;
        PhaseP P1 = { h0 + (size_t)cur0*HSZ, dWihb, h1 + (size_t)cur1*HSZ, dWhhb, 2,
                      nullptr, nullptr, 0, biases + 5*2048, c1, h1 + (size_t)(cur1^1)*HSZ };
        phase_k<<<256, thr, 0, stream>>>(P1); cur1 ^= 1;
        const ushort* h2p = (t == 0) ? (h2 + (size_t)HSZ) : (h2hist + (size_t)(t-1)*HSZ);
        PhaseP P2 = { h1 + (size_t)cur1*HSZ, dWihb + (size_t)WSZ, h2p, dWhhb + (size_t)WSZ, 2,
                      nullptr, nullptr, 0, biases + 6*2048, c2, h2hist + (size_t)t*HSZ };
        phase_k<<<256, thr, 0, stream>>>(P2);
      }
    }
    out_linear<<<1024, thr, 0, stream>>>(h2hist, lin_W, lin_b, (float*)d_out);
  } else {
    int cur0 = curF, cur1 = curF, cur2 = curF;
    for (int t = 0; t < 32; ++t){
      PhaseP P0 = { h0 + (size_t)cur0*HSZ, dWhh0b, nullptr, nullptr, 1,
                    dec_in, dec_Wih0, 2, biases + 3*2048, c0, h0 + (size_t)(cur0^1)*HSZ };
      phase_k<<<256, thr, 0, stream>>>(P0); cur0 ^= 1;
      PhaseP P1 = { h0 + (size_t)cur0*HSZ, dWihb, h1 + (size_t)cur1*HSZ, dWhhb, 2,
                    nullptr, nullptr, 0, biases + 5*2048, c1, h1 + (size_t)(cur1^1)*HSZ };
      phase_k<<<256, thr, 0, stream>>>(P1); cur1 ^= 1;
      PhaseP P2 = { h1 + (size_t)cur1*HSZ, dWihb + (size_t)WSZ, h2 + (size_t)cur2*HSZ, dWhhb + (size_t)WSZ, 2,
                    nullptr, nullptr, 0, biases + 6*2048, c2, h2 + (size_t)(cur2^1)*HSZ };
      phase_k<<<256, thr, 0, stream>>>(P2); cur2 ^= 1;
      dec_linear<<<32, thr, 0, stream>>>(h2 + (size_t)cur2*HSZ, lin_W, lin_b,
                                         (float*)d_out + (size_t)t*2048, dec_in);
    }
  }
}

// Round 6
// 3835.087 us; speedup vs baseline: 3.1755x; 3.1755x over previous
//
#include <hip/hip_runtime.h>
#include <hip/hip_bf16.h>

typedef __bf16 bf16x8 __attribute__((ext_vector_type(8)));
typedef float f32x4 __attribute__((ext_vector_type(4)));

#define HSZ (1024*512)      // h/c slot elems
#define WSZ (2048*512)      // weight matrix elems

__device__ __forceinline__ float fsig(float x){ return 1.0f/(1.0f+__expf(-x)); }
__device__ __forceinline__ float ftanh(float x){ return 1.0f - 2.0f/(__expf(2.0f*x)+1.0f); }

__device__ __forceinline__ void gload16(const void* g, void* l){
  __builtin_amdgcn_global_load_lds((const __attribute__((address_space(1))) void*)g,
                                   (__attribute__((address_space(3))) void*)l, 16, 0, 0);
}

struct Tid { int w, lane, wm, wn, colL, kgrp, srow, scch; };
__device__ __forceinline__ Tid mkTid(){
  Tid T; T.w = threadIdx.x >> 6; T.lane = threadIdx.x & 63;
  T.wm = T.w >> 1; T.wn = T.w & 1; T.colL = T.lane & 15; T.kgrp = T.lane >> 4;
  T.srow = T.lane >> 3; T.scch = T.lane & 7; return T;
}

struct SegT { const ushort* A; const ushort* W; };
struct CellD { int endit; const float* xs; const float* Ws; int ks;
               const float* bias; float* c; ushort* h; int valid; };

// stage one 64-K tile (A 64x64 + B 128x64 h-major-gate rows) into ring buffer `buf`
__device__ __forceinline__ void stage_buf(const ushort* A, const ushort* W, int k0,
                                          char* ldsb, int buf, int m0, int h0q, const Tid& T){
  ushort* Als = (ushort*)(ldsb + buf*24576);
  ushort* Bls = Als + 4096;
  #pragma unroll
  for (int q = 0; q < 2; ++q){
    const int base = (T.w<<4) + (q<<3);
    const int r = base + T.srow;
    const int sw = (T.scch ^ (r & 7)) << 3;
    gload16(A + (size_t)(m0 + r)*512 + k0 + sw, Als + base*64);
  }
  #pragma unroll
  for (int q = 0; q < 4; ++q){
    const int base = (T.w<<5) + (q<<3);
    const int r = base + T.srow;
    const int g = (r >> 4) & 3, hp = r >> 6, hh = r & 15;
    const int sw = (T.scch ^ (r & 7)) << 3;
    gload16(W + ((size_t)(g<<9) + h0q + (hp<<4) + hh)*512 + k0 + sw, Bls + base*64);
  }
}

__device__ __forceinline__ void mfma_step(char* ldsb, int buf, const Tid& T, f32x4 acc[2][4]){
  const ushort* Als = (const ushort*)(ldsb + buf*24576);
  const ushort* Bls = Als + 4096;
  const int ar0 = (T.wm<<5) + T.colL, ar1 = ar0 + 16;
  __builtin_amdgcn_s_setprio(1);
  #pragma unroll
  for (int kh = 0; kh < 2; ++kh){
    const int cb = (kh<<2) + T.kgrp;
    bf16x8 av0 = *(const bf16x8*)(Als + ar0*64 + ((cb ^ (ar0 & 7)) << 3));
    bf16x8 av1 = *(const bf16x8*)(Als + ar1*64 + ((cb ^ (ar1 & 7)) << 3));
    #pragma unroll
    for (int nf = 0; nf < 4; ++nf){
      const int br = (T.wn<<6) + (nf<<4) + T.colL;
      bf16x8 bv = *(const bf16x8*)(Bls + br*64 + ((cb ^ (br & 7)) << 3));
      acc[0][nf] = __builtin_amdgcn_mfma_f32_16x16x32_bf16(av0, bv, acc[0][nf], 0, 0, 0);
      acc[1][nf] = __builtin_amdgcn_mfma_f32_16x16x32_bf16(av1, bv, acc[1][nf], 0, 0, 0);
    }
  }
  __builtin_amdgcn_s_setprio(0);
}

__device__ __forceinline__ void cell_epi(const CellD& C, f32x4 acc[2][4], int m0, int h0q, const Tid& T){
  const int h = h0q + (T.wn<<4) + T.colL;
  float bia[4], wsv[4][4];
  #pragma unroll
  for (int g = 0; g < 4; ++g) bia[g] = C.bias[(g<<9) + h];
  if (C.ks > 0){
    #pragma unroll
    for (int g = 0; g < 4; ++g)
      #pragma unroll
      for (int k = 0; k < 4; ++k)
        wsv[g][k] = (k < C.ks) ? C.Ws[(size_t)((g<<9) + h)*C.ks + k] : 0.f;
  }
  #pragma unroll
  for (int mf = 0; mf < 2; ++mf){
    const int mB = m0 + (T.wm<<5) + (mf<<4) + (T.kgrp<<2);
    float xv[4][4];
    if (C.ks > 0){
      #pragma unroll
      for (int r = 0; r < 4; ++r)
        #pragma unroll
        for (int k = 0; k < 4; ++k)
          xv[r][k] = (k < C.ks) ? C.xs[(size_t)(mB + r)*C.ks + k] : 0.f;
    }
    #pragma unroll
    for (int r = 0; r < 4; ++r){
      const int m = mB + r;
      float gv[4];
      #pragma unroll
      for (int g = 0; g < 4; ++g){
        float t_ = acc[mf][g][r] + bia[g];
        if (C.ks > 0){
          #pragma unroll
          for (int k = 0; k < 4; ++k) t_ += xv[r][k]*wsv[g][k];
        }
        gv[g] = t_;
      }
      const float iG = fsig(gv[0]);
      const float fG = fsig(gv[1]);
      const float gG = ftanh(gv[2]);
      const float oG = fsig(gv[3]);
      const size_t off = (size_t)m*512 + h;
      const float cn = fG*C.c[off] + iG*gG;
      C.c[off] = cn;
      const float hv = oG*ftanh(cn);
      __hip_bfloat16 hb = __float2bfloat16(hv);
      C.h[off] = *reinterpret_cast<const ushort*>(&hb);
    }
  }
}

// one continuous pipelined stream of NT 64-K steps over <=5 segments / <=3 cells.
// ring-4 buffers, depth-3 prefetch, ONE barrier per K-step, counted vmcnt(12).
__device__ __forceinline__ void run_step(const SegT* seg, const CellD* cell, int ncell, int NT,
                                         char* ldsb, int m0, int h0q, const Tid& T){
  f32x4 acc[2][4];
  #pragma unroll
  for (int a = 0; a < 2; ++a)
    #pragma unroll
    for (int b = 0; b < 4; ++b)
      #pragma unroll
      for (int c = 0; c < 4; ++c) acc[a][b][c] = 0.f;

  auto sel = [&](int sgi, const ushort*& A, const ushort*& W){
    switch (sgi){
      case 0:  A = seg[0].A; W = seg[0].W; break;
      case 1:  A = seg[1].A; W = seg[1].W; break;
      case 2:  A = seg[2].A; W = seg[2].W; break;
      case 3:  A = seg[3].A; W = seg[3].W; break;
      default: A = seg[4].A; W = seg[4].W; break;
    }
  };

  #pragma unroll
  for (int it = 0; it < 3; ++it){
    const ushort *A, *W; sel(it >> 3, A, W);
    stage_buf(A, W, (it & 7) << 6, ldsb, it, m0, h0q, T);
  }
  for (int it = 0; it < NT; ++it){
    if (it < NT-2)       asm volatile("s_waitcnt vmcnt(12)" ::: "memory");
    else if (it == NT-2) asm volatile("s_waitcnt vmcnt(6)"  ::: "memory");
    else                 asm volatile("s_waitcnt vmcnt(0)"  ::: "memory");
    __builtin_amdgcn_s_barrier();
    __builtin_amdgcn_sched_barrier(0);
    if (it + 3 < NT){
      const int jt = it + 3;
      const ushort *A, *W; sel(jt >> 3, A, W);
      stage_buf(A, W, (jt & 7) << 6, ldsb, jt & 3, m0, h0q, T);
    }
    mfma_step(ldsb, it & 3, T, acc);
    __builtin_amdgcn_sched_barrier(0);
    bool bnd = false;
    if (it == cell[0].endit){ if (cell[0].valid) cell_epi(cell[0], acc, m0, h0q, T); bnd = true; }
    if (ncell > 1 && it == cell[1].endit){ if (cell[1].valid) cell_epi(cell[1], acc, m0, h0q, T); bnd = true; }
    if (ncell > 2 && it == cell[2].endit){ if (cell[2].valid) cell_epi(cell[2], acc, m0, h0q, T); bnd = true; }
    if (bnd){
      #pragma unroll
      for (int a = 0; a < 2; ++a)
        #pragma unroll
        for (int b = 0; b < 4; ++b)
          #pragma unroll
          for (int c = 0; c < 4; ++c) acc[a][b][c] = 0.f;
    }
  }
}

// ---------------- encoder ----------------
struct EncP { const float* x; const float* Wih0f;
  const ushort *Whh0, *Wih1, *Whh1, *Wih2, *Whh2;
  const float* biases; ushort *h0, *h1, *h2; float *c0, *c1, *c2; };

// wavefront step s: l0 t=s (K=512), l1 t=s-1 (K=1024), l2 t=s-2 (K=1024); h slots by parity
__device__ __forceinline__ void enc_build_run(const EncP& E, int s, char* lds, int m0, int h0q, const Tid& T){
  const int p = s & 1;
  SegT seg[5] = {
    { E.h0 + (size_t)(p^1)*HSZ, E.Whh0 },
    { E.h0 + (size_t)(p^1)*HSZ, E.Wih1 },
    { E.h1 + (size_t)p*HSZ,     E.Whh1 },
    { E.h1 + (size_t)p*HSZ,     E.Wih2 },
    { E.h2 + (size_t)(p^1)*HSZ, E.Whh2 },
  };
  CellD cell[3] = {
    { 7,  E.x + (size_t)(s <= 63 ? s : 63)*4096, E.Wih0f, 4, E.biases,      E.c0, E.h0 + (size_t)p*HSZ,     (int)(s <= 63) },
    { 23, nullptr, nullptr, 0,                   E.biases + 2048, E.c1, E.h1 + (size_t)(p^1)*HSZ, (int)(s >= 1 && s <= 64) },
    { 39, nullptr, nullptr, 0,                   E.biases + 4096, E.c2, E.h2 + (size_t)p*HSZ,     (int)(s >= 2) },
  };
  run_step(seg, cell, 3, 40, lds, m0, h0q, T);
}

__device__ __forceinline__ void wgmap(int f, int& m0, int& h0q){
  const int xcd = f & 7, j = f >> 3;
  m0  = (j & 15) << 6;
  h0q = (((j >> 4) << 3) + xcd) << 5;
}

__global__ __launch_bounds__(256) void enc_step_k(EncP E, int s){
  __shared__ char lds[98304];
  const Tid T = mkTid();
  int m0, h0q; wgmap(blockIdx.x, m0, h0q);
  enc_build_run(E, s, lds, m0, h0q, T);
}

// ---------------- decoder ----------------
struct PhaseP { const ushort *A0, *W0, *A1, *W1; int nseg;
  const float *xs, *Ws; int ks; const float* bias; float* c; ushort* h; };

__device__ __forceinline__ void phase_run(const PhaseP& P, char* lds, int m0, int h0q, const Tid& T){
  SegT seg[5];
  seg[0] = { P.A0, P.W0 };
  seg[1] = (P.nseg > 1) ? SegT{ P.A1, P.W1 } : seg[0];
  seg[2] = seg[1]; seg[3] = seg[1]; seg[4] = seg[1];
  const int NT = P.nseg * 8;
  CellD cell[3];
  cell[0] = { NT - 1, P.xs, P.Ws, P.ks, P.bias, P.c, P.h, 1 };
  cell[1] = cell[0]; cell[1].endit = -1; cell[1].valid = 0;
  cell[2] = cell[1];
  run_step(seg, cell, 1, NT, lds, m0, h0q, T);
}

__global__ __launch_bounds__(256) void phase_k(PhaseP P){
  __shared__ char lds[98304];
  const Tid T = mkTid();
  int m0, h0q; wgmap(blockIdx.x, m0, h0q);
  phase_run(P, lds, m0, h0q, T);
}

// ---------------- small utility kernels ----------------
__global__ void f2b4(const float4* __restrict__ src, ushort4* __restrict__ dst, int n4){
  int i = blockIdx.x*blockDim.x + threadIdx.x;
  if (i < n4){
    float4 v = src[i];
    __hip_bfloat16 a=__float2bfloat16(v.x), b=__float2bfloat16(v.y), c=__float2bfloat16(v.z), d=__float2bfloat16(v.w);
    ushort4 r;
    r.x = *reinterpret_cast<ushort*>(&a);
    r.y = *reinterpret_cast<ushort*>(&b);
    r.z = *reinterpret_cast<ushort*>(&c);
    r.w = *reinterpret_cast<ushort*>(&d);
    dst[i] = r;
  }
}

__global__ void init_decin(const float* __restrict__ x, float* __restrict__ di){
  int i = blockIdx.x*blockDim.x + threadIdx.x;
  if (i < 2048){ int m = i >> 1, j = i & 1; di[i] = x[(size_t)63*4096 + m*4 + j]; }
}

__global__ void make_wcomb(const float* __restrict__ dWih0, const float* __restrict__ linW,
                           ushort* __restrict__ wc){
  int i = blockIdx.x*blockDim.x + threadIdx.x;
  if (i < 2048*512){
    int n = i >> 9, k = i & 511;
    float v = dWih0[n*2]*linW[k] + dWih0[n*2+1]*linW[512+k];
    __hip_bfloat16 b = __float2bfloat16(v);
    wc[i] = *reinterpret_cast<ushort*>(&b);
  }
}

__global__ void prep_bias(const float* ebih0, const float* ebhh0,
                          const float* ebih, const float* ebhh,
                          const float* dbih0, const float* dbhh0,
                          const float* dbih, const float* dbhh,
                          const float* dWih0, const float* linb, float* bout){
  int n = blockIdx.x*blockDim.x + threadIdx.x;
  if (n >= 2048) return;
  bout[n]        = ebih0[n] + ebhh0[n];
  bout[2048+n]   = ebih[n] + ebhh[n];
  bout[2*2048+n] = ebih[2048+n] + ebhh[2048+n];
  float d0 = dbih0[n] + dbhh0[n];
  bout[3*2048+n] = d0;
  bout[4*2048+n] = d0 + dWih0[n*2]*linb[0] + dWih0[n*2+1]*linb[1];
  bout[5*2048+n] = dbih[n] + dbhh[n];
  bout[6*2048+n] = dbih[2048+n] + dbhh[2048+n];
}

__global__ __launch_bounds__(256) void out_linear(const ushort* __restrict__ h2,
    const float* __restrict__ linW, const float* __restrict__ linb, float* __restrict__ outp){
  int tid = threadIdx.x, w = tid >> 6, lane = tid & 63;
  int rbase = blockIdx.x*32 + w*8;
  for (int r = 0; r < 8; ++r){
    int m = rbase + r;
    float p0 = 0.f, p1 = 0.f;
    #pragma unroll
    for (int kk = 0; kk < 8; ++kk){
      int k = lane + kk*64;
      float hv = __uint_as_float(((unsigned)h2[(size_t)m*512 + k]) << 16);
      p0 += hv * linW[k];
      p1 += hv * linW[512 + k];
    }
    #pragma unroll
    for (int off = 32; off > 0; off >>= 1){
      p0 += __shfl_down(p0, off);
      p1 += __shfl_down(p1, off);
    }
    if (lane == 0){
      outp[(size_t)m*2]   = p0 + linb[0];
      outp[(size_t)m*2+1] = p1 + linb[1];
    }
  }
}

__global__ __launch_bounds__(256) void dec_linear(const ushort* __restrict__ h2,
    const float* __restrict__ linW, const float* __restrict__ linb,
    float* __restrict__ outp, float* __restrict__ di){
  int tid = threadIdx.x, w = tid >> 6, lane = tid & 63;
  int mbase = blockIdx.x*32 + w*8;
  for (int r = 0; r < 8; ++r){
    int m = mbase + r;
    float p0 = 0.f, p1 = 0.f;
    #pragma unroll
    for (int kk = 0; kk < 8; ++kk){
      int k = lane + kk*64;
      float hv = __uint_as_float(((unsigned)h2[(size_t)m*512 + k]) << 16);
      p0 += hv * linW[k];
      p1 += hv * linW[512 + k];
    }
    #pragma unroll
    for (int off = 32; off > 0; off >>= 1){
      p0 += __shfl_down(p0, off);
      p1 += __shfl_down(p1, off);
    }
    if (lane == 0){
      float o0 = p0 + linb[0], o1 = p1 + linb[1];
      outp[m*2]   = o0; outp[m*2+1] = o1;
      di[m*2]     = o0; di[m*2+1]   = o1;
    }
  }
}

extern "C" void kernel_launch(void* const* d_in, const int* in_sizes, int n_in,
                              void* d_out, int out_size, void* d_ws, size_t ws_size,
                              hipStream_t stream)
{
  const float* x        = (const float*)d_in[0];
  const float* enc_Wih0 = (const float*)d_in[1];
  const float* enc_Whh0 = (const float*)d_in[2];
  const float* enc_bih0 = (const float*)d_in[3];
  const float* enc_bhh0 = (const float*)d_in[4];
  const float* enc_Wih  = (const float*)d_in[5];
  const float* enc_Whh  = (const float*)d_in[6];
  const float* enc_bih  = (const float*)d_in[7];
  const float* enc_bhh  = (const float*)d_in[8];
  const float* dec_Wih0 = (const float*)d_in[9];
  const float* dec_Whh0 = (const float*)d_in[10];
  const float* dec_bih0 = (const float*)d_in[11];
  const float* dec_bhh0 = (const float*)d_in[12];
  const float* dec_Wih  = (const float*)d_in[13];
  const float* dec_Whh  = (const float*)d_in[14];
  const float* dec_bih  = (const float*)d_in[15];
  const float* dec_bhh  = (const float*)d_in[16];
  const float* lin_W    = (const float*)d_in[17];
  const float* lin_b    = (const float*)d_in[18];

  const bool big = ws_size >= 69271552ull;

  ushort* wb     = (ushort*)d_ws;
  ushort* eWhh0b = wb;
  ushort* eWihb  = wb + (size_t)WSZ;
  ushort* eWhhb  = wb + 3*(size_t)WSZ;
  ushort* dWhh0b = wb + 5*(size_t)WSZ;
  ushort* dWihb  = wb + 6*(size_t)WSZ;
  ushort* dWhhb  = wb + 8*(size_t)WSZ;
  ushort* wcombb = wb + 10*(size_t)WSZ;                   // big only
  ushort* hbuf   = wb + (big ? 11 : 10)*(size_t)WSZ;      // 6 HSZ (3 layers x 2 slots)
  ushort* h2hist = hbuf + 6*(size_t)HSZ;                  // big: 32 HSZ
  float*  cbuf   = (float*)(h2hist + (big ? 32*(size_t)HSZ : 0));
  float*  dec_in = cbuf + 3*(size_t)HSZ;
  float*  biases = dec_in + 2048;

  ushort* h0 = hbuf;
  ushort* h1 = hbuf + 2*(size_t)HSZ;
  ushort* h2 = hbuf + 4*(size_t)HSZ;
  float *c0 = cbuf, *c1 = cbuf + (size_t)HSZ, *c2 = cbuf + 2*(size_t)HSZ;

  hipMemsetAsync(hbuf, 0, 6*(size_t)HSZ*2, stream);
  hipMemsetAsync(cbuf, 0, 3*(size_t)HSZ*4, stream);

  const int thr = 256;
  {
    struct { const float* s; ushort* d; size_t n; } cv[6] = {
      {enc_Whh0, eWhh0b, WSZ}, {enc_Wih, eWihb, 2*(size_t)WSZ}, {enc_Whh, eWhhb, 2*(size_t)WSZ},
      {dec_Whh0, dWhh0b, WSZ}, {dec_Wih, dWihb, 2*(size_t)WSZ}, {dec_Whh, dWhhb, 2*(size_t)WSZ},
    };
    for (int i = 0; i < 6; ++i){
      int n4 = (int)(cv[i].n/4);
      f2b4<<<(n4+thr-1)/thr, thr, 0, stream>>>((const float4*)cv[i].s, (ushort4*)cv[i].d, n4);
    }
  }
  if (big) make_wcomb<<<4096, thr, 0, stream>>>(dec_Wih0, lin_W, wcombb);
  prep_bias<<<8, thr, 0, stream>>>(enc_bih0, enc_bhh0, enc_bih, enc_bhh,
                                   dec_bih0, dec_bhh0, dec_bih, dec_bhh,
                                   dec_Wih0, lin_b, biases);
  init_decin<<<8, thr, 0, stream>>>(x, dec_in);

  EncP EP = { x, enc_Wih0, eWhh0b, eWihb, eWhhb, eWihb + (size_t)WSZ, eWhhb + (size_t)WSZ,
              biases, h0, h1, h2, c0, c1, c2 };

  // ---- encoder: 66 fused wavefront-step launches (ring-4 depth-3 pipeline) ----
  for (int s = 0; s < 66; ++s)
    enc_step_k<<<256, thr, 0, stream>>>(EP, s);

  // encoder-final h slots: all layers' t=63 output lands in slot 1
  const int curF = 1;

  // ---- decoder ----
  if (big){
    int cur0 = curF, cur1 = curF;
    for (int t = 0; t < 32; ++t){
      PhaseP P0;
      if (t == 0) P0 = { h0 + (size_t)cur0*HSZ, dWhh0b, nullptr, nullptr, 1,
                         dec_in, dec_Wih0, 2, biases + 3*2048, c0, h0 + (size_t)(cur0^1)*HSZ };
      else        P0 = { h2hist + (size_t)(t-1)*HSZ, wcombb, h0 + (size_t)cur0*HSZ, dWhh0b, 2,
                         nullptr, nullptr, 0, biases + 4*2048, c0, h0 + (size_t)(cur0^1)*HSZ };
      phase_k<<<256, thr, 0, stream>>>(P0); cur0 ^= 1;
      PhaseP P1 = { h0 + (size_t)cur0*HSZ, dWihb, h1 + (size_t)cur1*HSZ, dWhhb, 2,
                    nullptr, nullptr, 0, biases + 5*2048, c1, h1 + (size_t)(cur1^1)*HSZ };
      phase_k<<<256, thr, 0, stream>>>(P1); cur1 ^= 1;
      const ushort* h2p = (t == 0) ? (h2 + (size_t)HSZ) : (h2hist + (size_t)(t-1)*HSZ);
      PhaseP P2 = { h1 + (size_t)cur1*HSZ, dWihb + (size_t)WSZ, h2p, dWhhb + (size_t)WSZ, 2,
                    nullptr, nullptr, 0, biases + 6*2048, c2, h2hist + (size_t)t*HSZ };
      phase_k<<<256, thr, 0, stream>>>(P2);
    }
    out_linear<<<1024, thr, 0, stream>>>(h2hist, lin_W, lin_b, (float*)d_out);
  } else {
    int cur0 = curF, cur1 = curF, cur2 = curF;
    for (int t = 0; t < 32; ++t){
      PhaseP P0 = { h0 + (size_t)cur0*HSZ, dWhh0b, nullptr, nullptr, 1,
                    dec_in, dec_Wih0, 2, biases + 3*2048, c0, h0 + (size_t)(cur0^1)*HSZ };
      phase_k<<<256, thr, 0, stream>>>(P0); cur0 ^= 1;
      PhaseP P1 = { h0 + (size_t)cur0*HSZ, dWihb, h1 + (size_t)cur1*HSZ, dWhhb, 2,
                    nullptr, nullptr, 0, biases + 5*2048, c1, h1 + (size_t)(cur1^1)*HSZ };
      phase_k<<<256, thr, 0, stream>>>(P1); cur1 ^= 1;
      PhaseP P2 = { h1 + (size_t)cur1*HSZ, dWihb + (size_t)WSZ, h2 + (size_t)cur2*HSZ, dWhhb + (size_t)WSZ, 2,
                    nullptr, nullptr, 0, biases + 6*2048, c2, h2 + (size_t)(cur2^1)*HSZ };
      phase_k<<<256, thr, 0, stream>>>(P2); cur2 ^= 1;
      dec_linear<<<32, thr, 0, stream>>>(h2 + (size_t)cur2*HSZ, lin_W, lin_b,
                                         (float*)d_out + (size_t)t*2048, dec_in);
    }
  }
}

// Round 7
// 2808.514 us; speedup vs baseline: 4.3362x; 1.3655x over previous
//
#include <hip/hip_runtime.h>
#include <hip/hip_bf16.h>

typedef __bf16 bf16x8 __attribute__((ext_vector_type(8)));
typedef float f32x4 __attribute__((ext_vector_type(4)));

#define HSZ (1024*512)      // h/c slot elems
#define WSZ (2048*512)      // weight matrix elems

__device__ __forceinline__ float fsig(float x){ return 1.0f/(1.0f+__expf(-x)); }
__device__ __forceinline__ float ftanh(float x){ return 1.0f - 2.0f/(__expf(2.0f*x)+1.0f); }
__device__ __forceinline__ float bf2f(ushort u){ return __uint_as_float(((unsigned)u) << 16); }
__device__ __forceinline__ ushort f2bf(float f){
  __hip_bfloat16 b = __float2bfloat16(f);
  return *reinterpret_cast<const ushort*>(&b);
}

__device__ __forceinline__ void gload16(const void* g, void* l){
  __builtin_amdgcn_global_load_lds((const __attribute__((address_space(1))) void*)g,
                                   (__attribute__((address_space(3))) void*)l, 16, 0, 0);
}

struct CellPar {
  const ushort* A0; const ushort* W0;   // bf16 segment 0 (A:[1024][512], W:[2048][512])
  const ushort* A1; const ushort* W1;   // bf16 segment 1 (null if absent)
  const float*  xs; const float* Ws; int ks;  // small-K fp32 part
  const float*  bias;                   // combined bias [2048]
  ushort* c; ushort* h_out;             // c is bf16 now
};

// WG tile: 64 batch x 128 gate-rows (4 gates x 32 h, h-major halves), 512 threads = 8 waves.
// Wave w: wm=w>>1 batch-quarter (16 rows), wn=w&1 h-half (16 h = 64 gate rows).
// Per K-step (K=64): wave does 2 kh x (1 av + 4 bv reads, 4 MFMA 16x16x32) = 8 MFMA.
// Ring-3 LDS buffers (24KB each = 72KB -> 2 WG/CU), depth-2 prefetch, counted vmcnt,
// pre-swizzled global source + XOR-swizzled LDS reads (2-way = free).
__device__ __forceinline__ void cell_body(const CellPar P, char* ldsb, int m0, int h0q)
{
  const int tid  = threadIdx.x;
  const int w    = tid >> 6, lane = tid & 63;
  const int wm   = w >> 1, wn = w & 1;
  const int colL = lane & 15, kgrp = lane >> 4;

  const ushort* Aseg[2] = { P.A0, P.A1 };
  const ushort* Wseg[2] = { P.W0, P.W1 };
  const int nt = (P.A1 != nullptr) ? 16 : 8;   // K-steps of 64 (8 per 512-K segment)

  auto stage = [&](int buf, int it){
    const int seg = it >> 3;
    const int k0  = (it & 7) << 6;
    const ushort* A  = Aseg[seg];
    const ushort* Wt = Wseg[seg];
    ushort* Als = (ushort*)(ldsb + buf*24576);
    ushort* Bls = Als + 4096;                     // +8KB
    {                                             // A: 64 rows, 1 instr/thread
      const int r  = tid >> 3, cc = tid & 7;
      const int sw = (cc ^ (r & 7)) << 3;
      gload16(A + (size_t)(m0 + r)*512 + k0 + sw, Als + (w << 9));
    }
    #pragma unroll
    for (int q = 0; q < 2; ++q){                  // B: 128 rows, 2 instr/thread
      const int rq = (q << 6) + (tid >> 3), cc = tid & 7;
      const int g = (rq >> 4) & 3, hp = rq >> 6, hh = rq & 15;
      const int sw = (cc ^ (rq & 7)) << 3;
      gload16(Wt + ((size_t)(g << 9) + h0q + (hp << 4) + hh)*512 + k0 + sw,
              Bls + (q << 12) + (w << 9));
    }
  };

  f32x4 acc[4] = {};

  stage(0, 0);
  stage(1, 1);
  for (int it = 0; it < nt; ++it){
    if (it + 2 < nt) stage((it + 2) % 3, it + 2);   // buffer (it-1)%3: reads done at prev barrier2
    if (it + 2 < nt)      asm volatile("s_waitcnt vmcnt(6)" ::: "memory");
    else if (it + 1 < nt) asm volatile("s_waitcnt vmcnt(3)" ::: "memory");
    else                  asm volatile("s_waitcnt vmcnt(0)" ::: "memory");
    __builtin_amdgcn_s_barrier();                   // all waves' stage(it) landed
    __builtin_amdgcn_sched_barrier(0);
    const ushort* Als = (const ushort*)(ldsb + (it % 3)*24576);
    const ushort* Bls = Als + 4096;
    const int ar = (wm << 4) + colL;
    __builtin_amdgcn_s_setprio(1);
    #pragma unroll
    for (int kh = 0; kh < 2; ++kh){
      const int cb = (kh << 2) + kgrp;
      bf16x8 av = *(const bf16x8*)(Als + ar*64 + ((cb ^ (ar & 7)) << 3));
      #pragma unroll
      for (int nf = 0; nf < 4; ++nf){
        const int br = (wn << 6) + (nf << 4) + colL;
        bf16x8 bv = *(const bf16x8*)(Bls + br*64 + ((cb ^ (br & 7)) << 3));
        acc[nf] = __builtin_amdgcn_mfma_f32_16x16x32_bf16(av, bv, acc[nf], 0, 0, 0);
      }
    }
    __builtin_amdgcn_s_setprio(0);
    __builtin_amdgcn_sched_barrier(0);
    __builtin_amdgcn_s_barrier();                   // reads done before buffer reuse
  }

  // ---- epilogue (gate index = nf, purely in-register) ----
  const int h  = h0q + (wn << 4) + colL;
  const int mB = m0 + (wm << 4) + (kgrp << 2);
  float bia[4], wsv[4][4], xv[4][4];
  #pragma unroll
  for (int g = 0; g < 4; ++g) bia[g] = P.bias[(g << 9) + h];
  if (P.ks > 0){
    #pragma unroll
    for (int g = 0; g < 4; ++g)
      #pragma unroll
      for (int k = 0; k < 4; ++k)
        wsv[g][k] = (k < P.ks) ? P.Ws[(size_t)((g << 9) + h)*P.ks + k] : 0.f;
    #pragma unroll
    for (int r = 0; r < 4; ++r)
      #pragma unroll
      for (int k = 0; k < 4; ++k)
        xv[r][k] = (k < P.ks) ? P.xs[(size_t)(mB + r)*P.ks + k] : 0.f;
  }
  #pragma unroll
  for (int r = 0; r < 4; ++r){
    const int m = mB + r;
    float gv[4];
    #pragma unroll
    for (int g = 0; g < 4; ++g){
      float t_ = acc[g][r] + bia[g];
      if (P.ks > 0){
        #pragma unroll
        for (int k = 0; k < 4; ++k) t_ += xv[r][k]*wsv[g][k];
      }
      gv[g] = t_;
    }
    const float iG = fsig(gv[0]);
    const float fG = fsig(gv[1]);
    const float gG = ftanh(gv[2]);
    const float oG = fsig(gv[3]);
    const size_t off = (size_t)m*512 + h;
    const float cn = fG*bf2f(P.c[off]) + iG*gG;     // c stored bf16; cn kept fp32 for h
    P.c[off] = f2bf(cn);
    const float hv = oG*ftanh(cn);
    P.h_out[off] = f2bf(hv);
  }
}

// decoder/generic cell: grid 256, XCD-pinned h-tiles (each XCD owns h-tiles {xcd, 8+xcd})
__global__ __launch_bounds__(512, 4) void cell_k(CellPar P){
  __shared__ char lds[73728];
  const int f = blockIdx.x;
  const int xcd = f & 7, j = f >> 3;          // j 0..31
  const int bx = j & 15, u = j >> 4;          // u 0..1
  cell_body(P, lds, bx << 6, ((u << 3) + xcd) << 5);
}

struct EncP { const float* x; const float* Wih0f;
  const ushort *Whh0, *Wih1, *Whh1, *Wih2, *Whh2;
  const float* biases; ushort *h0, *h1, *h2; ushort *c0, *c1, *c2; };

// encoder wavefront step s (R4 step-parity convention: slot = writing-step & 1).
// grid 768: per XCD: all 3 layers x h-tiles {xcd, 8+xcd} x 16 batch tiles.
__global__ __launch_bounds__(512, 4) void enc_step_k(EncP E, int s){
  __shared__ char lds[73728];
  const int f = blockIdx.x;
  const int xcd = f & 7, j = f >> 3;          // j 0..95
  const int bx = j & 15, u = j >> 4;          // u 0..5
  const int l = u >> 1, ht = ((u & 1) << 3) + xcd;
  const int t = s - l;
  if (t < 0 || t > 63) return;
  const int p = s & 1;
  CellPar P;
  if (l == 0){
    P = { E.h0 + (size_t)(p^1)*HSZ, E.Whh0, nullptr, nullptr,
          E.x + (size_t)t*4096, E.Wih0f, 4,
          E.biases, E.c0, E.h0 + (size_t)p*HSZ };
  } else {
    const ushort* hlm1 = (l == 1) ? E.h0 : E.h1;
    ushort* hl         = (l == 1) ? E.h1 : E.h2;
    ushort* cl         = (l == 1) ? E.c1 : E.c2;
    const ushort* Wih  = (l == 1) ? E.Wih1 : E.Wih2;
    const ushort* Whh  = (l == 1) ? E.Whh1 : E.Whh2;
    P = { hlm1 + (size_t)(p^1)*HSZ, Wih,
          hl   + (size_t)(p^1)*HSZ, Whh,
          nullptr, nullptr, 0,
          E.biases + l*2048, cl, hl + (size_t)p*HSZ };
  }
  cell_body(P, lds, bx << 6, ht << 5);
}

// ---------------- small utility kernels ----------------
__global__ void f2b4(const float4* __restrict__ src, ushort4* __restrict__ dst, int n4){
  int i = blockIdx.x*blockDim.x + threadIdx.x;
  if (i < n4){
    float4 v = src[i];
    ushort4 r;
    r.x = f2bf(v.x); r.y = f2bf(v.y); r.z = f2bf(v.z); r.w = f2bf(v.w);
    dst[i] = r;
  }
}

__global__ void init_decin(const float* __restrict__ x, float* __restrict__ di){
  int i = blockIdx.x*blockDim.x + threadIdx.x;
  if (i < 2048){ int m = i >> 1, j = i & 1; di[i] = x[(size_t)63*4096 + m*4 + j]; }
}

__global__ void make_wcomb(const float* __restrict__ dWih0, const float* __restrict__ linW,
                           ushort* __restrict__ wc){
  int i = blockIdx.x*blockDim.x + threadIdx.x;
  if (i < 2048*512){
    int n = i >> 9, k = i & 511;
    wc[i] = f2bf(dWih0[n*2]*linW[k] + dWih0[n*2+1]*linW[512+k]);
  }
}

__global__ void prep_bias(const float* ebih0, const float* ebhh0,
                          const float* ebih, const float* ebhh,
                          const float* dbih0, const float* dbhh0,
                          const float* dbih, const float* dbhh,
                          const float* dWih0, const float* linb, float* bout){
  int n = blockIdx.x*blockDim.x + threadIdx.x;
  if (n >= 2048) return;
  bout[n]        = ebih0[n] + ebhh0[n];
  bout[2048+n]   = ebih[n] + ebhh[n];
  bout[2*2048+n] = ebih[2048+n] + ebhh[2048+n];
  float d0 = dbih0[n] + dbhh0[n];
  bout[3*2048+n] = d0;
  bout[4*2048+n] = d0 + dWih0[n*2]*linb[0] + dWih0[n*2+1]*linb[1];
  bout[5*2048+n] = dbih[n] + dbhh[n];
  bout[6*2048+n] = dbih[2048+n] + dbhh[2048+n];
}

__global__ __launch_bounds__(256) void out_linear(const ushort* __restrict__ h2,
    const float* __restrict__ linW, const float* __restrict__ linb, float* __restrict__ outp){
  int tid = threadIdx.x, w = tid >> 6, lane = tid & 63;
  int rbase = blockIdx.x*32 + w*8;
  for (int r = 0; r < 8; ++r){
    int m = rbase + r;
    float p0 = 0.f, p1 = 0.f;
    #pragma unroll
    for (int kk = 0; kk < 8; ++kk){
      int k = lane + kk*64;
      float hv = bf2f(h2[(size_t)m*512 + k]);
      p0 += hv * linW[k];
      p1 += hv * linW[512 + k];
    }
    #pragma unroll
    for (int off = 32; off > 0; off >>= 1){
      p0 += __shfl_down(p0, off);
      p1 += __shfl_down(p1, off);
    }
    if (lane == 0){
      outp[(size_t)m*2]   = p0 + linb[0];
      outp[(size_t)m*2+1] = p1 + linb[1];
    }
  }
}

__global__ __launch_bounds__(256) void dec_linear(const ushort* __restrict__ h2,
    const float* __restrict__ linW, const float* __restrict__ linb,
    float* __restrict__ outp, float* __restrict__ di){
  int tid = threadIdx.x, w = tid >> 6, lane = tid & 63;
  int mbase = blockIdx.x*32 + w*8;
  for (int r = 0; r < 8; ++r){
    int m = mbase + r;
    float p0 = 0.f, p1 = 0.f;
    #pragma unroll
    for (int kk = 0; kk < 8; ++kk){
      int k = lane + kk*64;
      float hv = bf2f(h2[(size_t)m*512 + k]);
      p0 += hv * linW[k];
      p1 += hv * linW[512 + k];
    }
    #pragma unroll
    for (int off = 32; off > 0; off >>= 1){
      p0 += __shfl_down(p0, off);
      p1 += __shfl_down(p1, off);
    }
    if (lane == 0){
      float o0 = p0 + linb[0], o1 = p1 + linb[1];
      outp[m*2]   = o0; outp[m*2+1] = o1;
      di[m*2]     = o0; di[m*2+1]   = o1;
    }
  }
}

extern "C" void kernel_launch(void* const* d_in, const int* in_sizes, int n_in,
                              void* d_out, int out_size, void* d_ws, size_t ws_size,
                              hipStream_t stream)
{
  const float* x        = (const float*)d_in[0];
  const float* enc_Wih0 = (const float*)d_in[1];
  const float* enc_Whh0 = (const float*)d_in[2];
  const float* enc_bih0 = (const float*)d_in[3];
  const float* enc_bhh0 = (const float*)d_in[4];
  const float* enc_Wih  = (const float*)d_in[5];
  const float* enc_Whh  = (const float*)d_in[6];
  const float* enc_bih  = (const float*)d_in[7];
  const float* enc_bhh  = (const float*)d_in[8];
  const float* dec_Wih0 = (const float*)d_in[9];
  const float* dec_Whh0 = (const float*)d_in[10];
  const float* dec_bih0 = (const float*)d_in[11];
  const float* dec_bhh0 = (const float*)d_in[12];
  const float* dec_Wih  = (const float*)d_in[13];
  const float* dec_Whh  = (const float*)d_in[14];
  const float* dec_bih  = (const float*)d_in[15];
  const float* dec_bhh  = (const float*)d_in[16];
  const float* lin_W    = (const float*)d_in[17];
  const float* lin_b    = (const float*)d_in[18];

  const bool big = ws_size >= 69271552ull;

  ushort* wb     = (ushort*)d_ws;
  ushort* eWhh0b = wb;
  ushort* eWihb  = wb + (size_t)WSZ;
  ushort* eWhhb  = wb + 3*(size_t)WSZ;
  ushort* dWhh0b = wb + 5*(size_t)WSZ;
  ushort* dWihb  = wb + 6*(size_t)WSZ;
  ushort* dWhhb  = wb + 8*(size_t)WSZ;
  ushort* wcombb = wb + 10*(size_t)WSZ;                   // big only
  ushort* hbuf   = wb + (big ? 11 : 10)*(size_t)WSZ;      // 6 HSZ (3 layers x 2 slots)
  ushort* h2hist = hbuf + 6*(size_t)HSZ;                  // big: 32 HSZ
  ushort* cbuf   = h2hist + (big ? 32*(size_t)HSZ : 0);   // bf16 c, 3 HSZ
  float*  dec_in = (float*)(cbuf + 3*(size_t)HSZ);
  float*  biases = dec_in + 2048;

  ushort* h0 = hbuf;
  ushort* h1 = hbuf + 2*(size_t)HSZ;
  ushort* h2 = hbuf + 4*(size_t)HSZ;
  ushort *c0 = cbuf, *c1 = cbuf + (size_t)HSZ, *c2 = cbuf + 2*(size_t)HSZ;

  hipMemsetAsync(hbuf, 0, 6*(size_t)HSZ*2, stream);
  hipMemsetAsync(cbuf, 0, 3*(size_t)HSZ*2, stream);

  const int thr = 256;
  {
    struct { const float* s; ushort* d; size_t n; } cv[6] = {
      {enc_Whh0, eWhh0b, WSZ}, {enc_Wih, eWihb, 2*(size_t)WSZ}, {enc_Whh, eWhhb, 2*(size_t)WSZ},
      {dec_Whh0, dWhh0b, WSZ}, {dec_Wih, dWihb, 2*(size_t)WSZ}, {dec_Whh, dWhhb, 2*(size_t)WSZ},
    };
    for (int i = 0; i < 6; ++i){
      int n4 = (int)(cv[i].n/4);
      f2b4<<<(n4+thr-1)/thr, thr, 0, stream>>>((const float4*)cv[i].s, (ushort4*)cv[i].d, n4);
    }
  }
  if (big) make_wcomb<<<4096, thr, 0, stream>>>(dec_Wih0, lin_W, wcombb);
  prep_bias<<<8, thr, 0, stream>>>(enc_bih0, enc_bhh0, enc_bih, enc_bhh,
                                   dec_bih0, dec_bhh0, dec_bih, dec_bhh,
                                   dec_Wih0, lin_b, biases);
  init_decin<<<8, thr, 0, stream>>>(x, dec_in);

  EncP EP = { x, enc_Wih0, eWhh0b, eWihb, eWhhb, eWihb + (size_t)WSZ, eWhhb + (size_t)WSZ,
              biases, h0, h1, h2, c0, c1, c2 };

  // ---- encoder: 66 wavefront-step launches, 768 WGs x 512 thr (2 WG/CU) ----
  for (int s = 0; s < 66; ++s)
    enc_step_k<<<768, 512, 0, stream>>>(EP, s);

  // encoder finals (step-parity slots): l0 @s=63 -> 1, l1 @s=64 -> 0, l2 @s=65 -> 1
  int cur0 = 1, cur1 = 0, cur2 = 1;

  // ---- decoder ----
  if (big){
    for (int t = 0; t < 32; ++t){
      CellPar P0;
      if (t == 0)
        P0 = { h0 + (size_t)cur0*HSZ, dWhh0b, nullptr, nullptr,
               dec_in, dec_Wih0, 2, biases + 3*2048, c0, h0 + (size_t)(cur0^1)*HSZ };
      else
        P0 = { h2hist + (size_t)(t-1)*HSZ, wcombb, h0 + (size_t)cur0*HSZ, dWhh0b,
               nullptr, nullptr, 0, biases + 4*2048, c0, h0 + (size_t)(cur0^1)*HSZ };
      cell_k<<<256, 512, 0, stream>>>(P0); cur0 ^= 1;

      CellPar P1 = { h0 + (size_t)cur0*HSZ, dWihb, h1 + (size_t)cur1*HSZ, dWhhb,
                     nullptr, nullptr, 0, biases + 5*2048, c1, h1 + (size_t)(cur1^1)*HSZ };
      cell_k<<<256, 512, 0, stream>>>(P1); cur1 ^= 1;

      const ushort* a2prev = (t == 0) ? (h2 + (size_t)cur2*HSZ) : (h2hist + (size_t)(t-1)*HSZ);
      CellPar P2 = { h1 + (size_t)cur1*HSZ, dWihb + (size_t)WSZ, a2prev, dWhhb + (size_t)WSZ,
                     nullptr, nullptr, 0, biases + 6*2048, c2, h2hist + (size_t)t*HSZ };
      cell_k<<<256, 512, 0, stream>>>(P2);
    }
    out_linear<<<1024, thr, 0, stream>>>(h2hist, lin_W, lin_b, (float*)d_out);
  } else {
    for (int t = 0; t < 32; ++t){
      CellPar P0 = { h0 + (size_t)cur0*HSZ, dWhh0b, nullptr, nullptr,
                     dec_in, dec_Wih0, 2, biases + 3*2048, c0, h0 + (size_t)(cur0^1)*HSZ };
      cell_k<<<256, 512, 0, stream>>>(P0); cur0 ^= 1;

      CellPar P1 = { h0 + (size_t)cur0*HSZ, dWihb, h1 + (size_t)cur1*HSZ, dWhhb,
                     nullptr, nullptr, 0, biases + 5*2048, c1, h1 + (size_t)(cur1^1)*HSZ };
      cell_k<<<256, 512, 0, stream>>>(P1); cur1 ^= 1;

      CellPar P2 = { h1 + (size_t)cur1*HSZ, dWihb + (size_t)WSZ,
                     h2 + (size_t)cur2*HSZ, dWhhb + (size_t)WSZ,
                     nullptr, nullptr, 0, biases + 6*2048, c2, h2 + (size_t)(cur2^1)*HSZ };
      cell_k<<<256, 512, 0, stream>>>(P2); cur2 ^= 1;

      dec_linear<<<32, thr, 0, stream>>>(h2 + (size_t)cur2*HSZ, lin_W, lin_b,
                                         (float*)d_out + (size_t)t*2048, dec_in);
    }
  }
}